// Round 15
// baseline (732.444 us; speedup 1.0000x reference)
//
#include <hip/hip_runtime.h>

// GraphConv GNN forward, MI355X — Round 15.
// R14: agg 4x unroll neutral -> gather tier is L2/fabric-throughput-bound, not
// issue-bound. This round attacks dispatch count + CSR-tier work the RIGHT way
// (R13 lesson: fuse by parallel block ranges, never serialize):
//  - histprep_kernel: blocks 0..255 do edge histogram (global-atomic gcount),
//    blocks 256+ do prep (cvt/pack/fold) CONCURRENTLY; done-counter tail block
//    scans gcount -> bsum/roff. Replaces hist+scan1+scan2+prep (4 dispatches).
//  - partition_v2: block-local LDS histogram (L2-hot re-read) + 256 global
//    atomic reservations -> no bcnt array, no 64k scan.
// Aggs/GEMMs/pool identical to R14 (251.9us). 14 -> 11 dispatches.

#define NNODES 50000
#define NEDGES 800000
#define NGRAPH 64
#define NBUK 256                          // dst buckets
#define BSZ 196                           // nodes per bucket (196*256 >= 50000)
#define EPB (NEDGES / NBUK)               // 3125 edges per partition block
#define CVT_NB (NNODES * 128 / 4 / 256)   // 6250
#define PACK_NB (160 * 512 / 256)         // 320
#define PREP_NB (CVT_NB + PACK_NB + 1)    // 6571
#define RGRID ((NNODES + 127) / 128)      // 391 row blocks
#define RCHUNK ((RGRID + 7) / 8)          // 49 chunks of 8 row blocks

typedef __attribute__((ext_vector_type(8))) __bf16 bf16x8;
typedef __attribute__((ext_vector_type(16))) float f32x16;

__device__ __forceinline__ unsigned short f2bf(float f) {
    unsigned u = __float_as_uint(f);
    u += 0x7fff + ((u >> 16) & 1);   // RNE
    return (unsigned short)(u >> 16);
}
__device__ __forceinline__ float bf2f(unsigned b) {
    return __uint_as_float(b << 16);
}

// async 16B global->LDS DMA; LDS dest is wave-uniform base + lane*16 [m104]
__device__ __forceinline__ void dma16(const void* g, void* l) {
    __builtin_amdgcn_global_load_lds(
        (const __attribute__((address_space(1))) void*)g,
        (__attribute__((address_space(3))) void*)l, 16, 0, 0);
}

// ---------------- prep body (cvt / weight pack / head fold) ------------------

__device__ __forceinline__ void pack32(const float* __restrict__ W, unsigned short* __restrict__ dst,
                                       int KS_tot, int ks0, int dcols, int ct0,
                                       int tl, int ksl, int lane, int j) {
    int k = ksl * 16 + ((lane >> 5) << 3) + j;
    int col = tl * 32 + (lane & 31);
    dst[(((size_t)(ct0 + tl) * KS_tot + (ks0 + ksl)) * 64 + lane) * 8 + j] = f2bf(W[k * dcols + col]);
}

__device__ void prep_body(int b, int tid,
                          const float* x, unsigned short* xbf,
                          const float* w1_rel, const float* w1_root,
                          const float* w2_rel, const float* w2_root,
                          const float* w3_rel, const float* w3_root,
                          unsigned short* pL1, unsigned short* pL2, unsigned short* pL3,
                          const float* w4_rel, const float* w4_root,
                          const float* b4, const float* head_w,
                          float* wr, float* wt, float* cbuf) {
    if (b < CVT_NB) {                       // fp32 -> bf16 of x
        int i = b * 256 + tid;
        float4 v = ((const float4*)x)[i];
        unsigned lo = (unsigned)f2bf(v.x) | ((unsigned)f2bf(v.y) << 16);
        unsigned hi = (unsigned)f2bf(v.z) | ((unsigned)f2bf(v.w) << 16);
        ((uint2*)xbf)[i] = make_uint2(lo, hi);
    } else if (b < CVT_NB + PACK_NB) {      // weight packing (32x32x16 B-frag order)
        int idx = (b - CVT_NB) * 256 + tid;
        int g = idx >> 9;
        int t = idx & 511;
        int lane = (t >> 3) & 63, j = t & 7;
        if (g < 16)       { int gl = g;       pack32(w1_rel,  pL1, 8,  0, 64,  0, gl / 8, gl % 8, lane, j); }
        else if (g < 32)  { int gl = g - 16;  pack32(w1_root, pL1, 8,  0, 64,  2, gl / 8, gl % 8, lane, j); }
        else if (g < 48)  { int gl = g - 32;  pack32(w2_rel,  pL2, 8,  0, 128, 0, gl / 4, gl % 4, lane, j); }
        else if (g < 64)  { int gl = g - 48;  pack32(w2_root, pL2, 8,  4, 128, 0, gl / 4, gl % 4, lane, j); }
        else if (g < 112) { int gl = g - 64;  pack32(w3_rel,  pL3, 16, 0, 192, 0, gl / 8, gl % 8, lane, j); }
        else              { int gl = g - 112; pack32(w3_root, pL3, 16, 8, 192, 0, gl / 8, gl % 8, lane, j); }
    } else {                                // head folding
        if (tid < 192) {
            float ar = 0.f, at = 0.f;
            for (int j = 0; j < 64; j++) {
                float hw = head_w[j];
                ar = fmaf(w4_rel[tid * 64 + j], hw, ar);
                at = fmaf(w4_root[tid * 64 + j], hw, at);
            }
            wr[tid] = ar;
            wt[tid] = at;
        } else if (tid == 192) {
            float c = 0.f;
            for (int j = 0; j < 64; j++) c = fmaf(b4[j], head_w[j], c);
            cbuf[0] = c;
        }
    }
}

// ---------------- fused hist + prep (parallel block ranges) + scan tail ------

__global__ void __launch_bounds__(256) histprep_kernel(
    const int* __restrict__ edst, int* __restrict__ gcount,
    int* __restrict__ bsum, int* __restrict__ roff, int* __restrict__ done,
    const float* __restrict__ x, unsigned short* __restrict__ xbf,
    const float* __restrict__ w1_rel, const float* __restrict__ w1_root,
    const float* __restrict__ w2_rel, const float* __restrict__ w2_root,
    const float* __restrict__ w3_rel, const float* __restrict__ w3_root,
    unsigned short* __restrict__ pL1, unsigned short* __restrict__ pL2,
    unsigned short* __restrict__ pL3,
    const float* __restrict__ w4_rel, const float* __restrict__ w4_root,
    const float* __restrict__ b4, const float* __restrict__ head_w,
    float* __restrict__ wr, float* __restrict__ wt, float* __restrict__ cbuf)
{
    __shared__ int sm[256];
    __shared__ int lastflag;
    int tid = threadIdx.x, b = blockIdx.x;
    if (b < NBUK) {                          // histogram of edge chunk b
        sm[tid] = 0;
        __syncthreads();
        int end = (b + 1) * EPB;
        for (int i = b * EPB + tid; i < end; i += 256)
            atomicAdd(&sm[edst[i] / BSZ], 1);
        __syncthreads();
        if (sm[tid]) atomicAdd(&gcount[tid], sm[tid]);
    } else {                                 // prep work, full parallelism
        prep_body(b - NBUK, tid, x, xbf, w1_rel, w1_root, w2_rel, w2_root,
                  w3_rel, w3_root, pL1, pL2, pL3, w4_rel, w4_root, b4, head_w,
                  wr, wt, cbuf);
    }
    __threadfence();
    __syncthreads();
    if (tid == 0) {
        int d = atomicAdd(done, 1);
        lastflag = (d == (int)gridDim.x - 1);
    }
    __syncthreads();
    if (lastflag) {                          // tail: 256-entry exclusive scan
        int v = atomicAdd(&gcount[tid], 0);  // device-coherent read
        sm[tid] = v;
        __syncthreads();
        #pragma unroll
        for (int off = 1; off < 256; off <<= 1) {
            int t = (tid >= off) ? sm[tid - off] : 0;
            __syncthreads();
            sm[tid] += t;
            __syncthreads();
        }
        int base = sm[tid] - v;
        bsum[tid] = base;                    // bucket bases (for build)
        roff[tid] = base;                    // mutable cursors (for partition)
    }
}

// ---------------- partition v2: local hist + atomic reservation --------------

__global__ void partition_kernel(const int* __restrict__ esrc, const int* __restrict__ edst,
                                 int* __restrict__ roff,
                                 unsigned long long* __restrict__ pedge) {
    __shared__ int cur[NBUK];
    int tid = threadIdx.x, k = blockIdx.x;
    cur[tid] = 0;
    __syncthreads();
    int end = (k + 1) * EPB;
    for (int i = k * EPB + tid; i < end; i += 256)
        atomicAdd(&cur[edst[i] / BSZ], 1);   // block-local histogram (L2-hot)
    __syncthreads();
    int cnt = cur[tid];
    cur[tid] = cnt ? atomicAdd(&roff[tid], cnt) : 0;   // reserve [base, base+cnt)
    __syncthreads();
    for (int i = k * EPB + tid; i < end; i += 256) {
        int s = esrc[i], d = edst[i];
        int pos = atomicAdd(&cur[d / BSZ], 1);
        pedge[pos] = (unsigned long long)(unsigned)s | ((unsigned long long)(unsigned)d << 32);
    }
}

__global__ void build_kernel(const unsigned long long* __restrict__ pedge,
                             const int* __restrict__ bsum,
                             int* __restrict__ rp, int* __restrict__ csr) {
    __shared__ int sdeg[256], sc[256], sbase[256], sfill[256];
    int tid = threadIdx.x, b = blockIdx.x;
    int node0 = b * BSZ;
    int ncnt = NNODES - node0;
    if (ncnt > BSZ) ncnt = BSZ;
    if (ncnt < 0) ncnt = 0;
    int seg0 = bsum[b];
    int seg1 = (b + 1 < NBUK) ? bsum[b + 1] : NEDGES;
    sdeg[tid] = 0;
    sfill[tid] = 0;
    __syncthreads();
    for (int i = seg0 + tid; i < seg1; i += 256)
        atomicAdd(&sdeg[(int)(pedge[i] >> 32) - node0], 1);
    __syncthreads();
    sc[tid] = sdeg[tid];
    __syncthreads();
    #pragma unroll
    for (int off = 1; off < 256; off <<= 1) {
        int t = (tid >= off) ? sc[tid - off] : 0;
        __syncthreads();
        sc[tid] += t;
        __syncthreads();
    }
    sbase[tid] = sc[tid] - sdeg[tid];          // exclusive within bucket
    if (tid < ncnt) rp[node0 + tid] = seg0 + sbase[tid];
    if (b == NBUK - 1 && tid == 0) rp[NNODES] = NEDGES;
    __syncthreads();
    for (int i = seg0 + tid; i < seg1; i += 256) {
        unsigned long long p = pedge[i];
        int d = (int)(p >> 32) - node0;
        int pos = atomicAdd(&sfill[d], 1);
        csr[seg0 + sbase[d] + pos] = (int)(p & 0xffffffffu);
    }
}

// ---------------- MFMA GEMM v5: LDS-resident via async DMA (R12, unchanged) --

template<int KS, int NT, int NHALF, int ST, int KCH>
__global__ __launch_bounds__(256) void gemm_v5(
    const unsigned short* __restrict__ A, const unsigned short* __restrict__ Wall,
    const float* __restrict__ bias, unsigned short* __restrict__ OUT,
    int ldo, int ocol0, int relu, int N,
    const float* __restrict__ wrp, const float* __restrict__ wtp,
    float* __restrict__ sb, float* __restrict__ tb)
{
    const int K = KS * 16;                  // elements (shorts) per row
    const int CPC = KCH * 2;                // 16B chunks per row per A-chunk
    __shared__ __align__(16) unsigned short sB[NT * KS * 512];
    __shared__ __align__(16) unsigned short sA[128 * KCH * 16];

    int i = blockIdx.x;
    int chunk = i / (8 * NHALF);
    int rem = i - chunk * (8 * NHALF);
    int halfsel = rem >> 3;
    int rowb = chunk * 8 + (rem & 7);       // halves of a rowb share blockIdx%8
    int rbase = rowb * 128;
    if (rbase >= N) return;                 // uniform per block

    int tid = threadIdx.x;
    int wave = tid >> 6, lane = tid & 63;
    int l32 = lane & 31, half = lane >> 5;
    const unsigned short* W = Wall + (size_t)halfsel * NT * KS * 512;

    // stage B once (linear)
    #pragma unroll
    for (int j = 0; j < NT * KS * 64 / 256; j++) {
        int p = j * 256 + wave * 64;        // wave-uniform base unit
        dma16(W + ((size_t)p + lane) * 8, sB + (size_t)p * 8);
    }

    f32x16 acc[NT];
    #pragma unroll
    for (int t = 0; t < NT; t++)
        #pragma unroll
        for (int r = 0; r < 16; r++) acc[t][r] = 0.f;

    int lr = wave * 32 + l32;               // local row of this lane's A frags

    for (int kb = 0; kb < KS; kb += KCH) {
        if (kb > 0) __syncthreads();        // protect sA overwrite
        // stage A chunk: 128 rows x KCH ks, XOR-swizzled 16B chunks
        #pragma unroll
        for (int j = 0; j < 128 * CPC / 256; j++) {
            int p = j * 256 + wave * 64 + lane;
            int r = p / CPC;
            int c = p - r * CPC;
            int cg = c ^ (r & (CPC - 1));
            dma16(A + (size_t)(rbase + r) * K + kb * 16 + cg * 8,
                  sA + (size_t)(j * 256 + wave * 64) * 8);
        }
        __syncthreads();                    // drains vmcnt before barrier
        #pragma unroll
        for (int l = 0; l < KCH; l++) {
            int cs = (l * 2 + half) ^ (lr & (CPC - 1));
            bf16x8 a = *(const bf16x8*)(sA + (size_t)lr * (KCH * 16) + cs * 8);
            int ks = kb + l;
            #pragma unroll
            for (int t = 0; t < NT; t++) {
                bf16x8 b = *(const bf16x8*)(sB + ((size_t)(t * KS + ks) * 64 + lane) * 8);
                acc[t] = __builtin_amdgcn_mfma_f32_32x32x16_bf16(a, b, acc[t], 0, 0, 0);
            }
        }
    }

    int wrbase = rbase + wave * 32;
    if constexpr (ST) {
        // fused L4 projection: partial s/t per row via shfl reduce + atomicAdd
        #pragma unroll
        for (int reg = 0; reg < 16; reg++) {
            int row = wrbase + (reg & 3) + 8 * (reg >> 2) + 4 * half;
            float sv = 0.f, tv = 0.f;
            #pragma unroll
            for (int t = 0; t < NT; t++) {
                int col = halfsel * NT * 32 + t * 32 + l32;
                float v = fmaxf(acc[t][reg] + bias[col], 0.f);
                sv = fmaf(v, wrp[col], sv);
                tv = fmaf(v, wtp[col], tv);
            }
            #pragma unroll
            for (int m = 1; m < 32; m <<= 1) {
                sv += __shfl_xor(sv, m, 64);
                tv += __shfl_xor(tv, m, 64);
            }
            if (l32 == 0 && row < N) {
                atomicAdd(&sb[row], sv);
                atomicAdd(&tb[row], tv);
            }
        }
    } else {
        #pragma unroll
        for (int t = 0; t < NT; t++) {
            int col = t * 32 + l32;
            float bi = bias ? bias[col] : 0.f;
            #pragma unroll
            for (int reg = 0; reg < 16; reg++) {
                int row = wrbase + (reg & 3) + 8 * (reg >> 2) + 4 * half;
                if (row < N) {
                    float v = acc[t][reg] + bi;
                    if (relu) v = fmaxf(v, 0.f);
                    OUT[(size_t)row * ldo + ocol0 + col] = f2bf(v);
                }
            }
        }
    }
}

// ---------------- bf16 neighbor-sum via CSR gather (R14, unchanged) ----------

__device__ __forceinline__ void acc8(float* a, uint4 u) {
    a[0] += bf2f(u.x & 0xffffu); a[1] += bf2f(u.x >> 16);
    a[2] += bf2f(u.y & 0xffffu); a[3] += bf2f(u.y >> 16);
    a[4] += bf2f(u.z & 0xffffu); a[5] += bf2f(u.z >> 16);
    a[6] += bf2f(u.w & 0xffffu); a[7] += bf2f(u.w >> 16);
}

template<int LPF, int SUBS>
__global__ void agg_kernel_v4(const unsigned short* __restrict__ X, int ldx,
                              const int* __restrict__ rp, const int* __restrict__ csr,
                              const unsigned short* __restrict__ root, int ldr,
                              const float* __restrict__ bias, int relu,
                              unsigned short* __restrict__ OUT, int ldo, int N) {
    int t = blockIdx.x * blockDim.x + threadIdx.x;
    int node = t / (SUBS * LPF);
    int r = t % (SUBS * LPF);
    int sub = r / LPF;
    int sl = r % LPF;
    if (node >= N) return;
    float a[8] = {0.f, 0.f, 0.f, 0.f, 0.f, 0.f, 0.f, 0.f};
    int e0 = rp[node], e1 = rp[node + 1];
    const unsigned short* xb = X + 8 * sl;
    int e = e0 + sub;
    for (; e + 3 * SUBS < e1; e += 4 * SUBS) {    // 4 independent gathers in flight
        int s0 = csr[e], s1 = csr[e + SUBS], s2 = csr[e + 2 * SUBS], s3 = csr[e + 3 * SUBS];
        uint4 u0 = *(const uint4*)(xb + (size_t)s0 * ldx);
        uint4 u1 = *(const uint4*)(xb + (size_t)s1 * ldx);
        uint4 u2 = *(const uint4*)(xb + (size_t)s2 * ldx);
        uint4 u3 = *(const uint4*)(xb + (size_t)s3 * ldx);
        acc8(a, u0); acc8(a, u1); acc8(a, u2); acc8(a, u3);
    }
    for (; e < e1; e += SUBS) {
        uint4 u = *(const uint4*)(xb + (size_t)csr[e] * ldx);
        acc8(a, u);
    }
    #pragma unroll
    for (int m = LPF; m < SUBS * LPF; m <<= 1)
        #pragma unroll
        for (int i = 0; i < 8; i++) a[i] += __shfl_xor(a[i], m, 64);
    if (sub == 0) {
        if (root) {
            uint4 u = *(const uint4*)(root + (size_t)node * ldr + 8 * sl);
            acc8(a, u);
        }
        if (bias) {
            float4 b0 = *(const float4*)(bias + 8 * sl);
            float4 b1 = *(const float4*)(bias + 8 * sl + 4);
            a[0] += b0.x; a[1] += b0.y; a[2] += b0.z; a[3] += b0.w;
            a[4] += b1.x; a[5] += b1.y; a[6] += b1.z; a[7] += b1.w;
        }
        if (relu) {
            #pragma unroll
            for (int i = 0; i < 8; i++) a[i] = fmaxf(a[i], 0.f);
        }
        uint4 o;
        o.x = (unsigned)f2bf(a[0]) | ((unsigned)f2bf(a[1]) << 16);
        o.y = (unsigned)f2bf(a[2]) | ((unsigned)f2bf(a[3]) << 16);
        o.z = (unsigned)f2bf(a[4]) | ((unsigned)f2bf(a[5]) << 16);
        o.w = (unsigned)f2bf(a[6]) | ((unsigned)f2bf(a[7]) << 16);
        *(uint4*)(OUT + (size_t)node * ldo + 8 * sl) = o;
    }
}

// ---------------- pool + head (R14 shape, unchanged) -------------------------

__global__ void aggpool_kernel(const float* __restrict__ s, const float* __restrict__ t,
                               const int* __restrict__ rp, const int* __restrict__ csr,
                               const int* __restrict__ batch, float* __restrict__ gsum,
                               int* __restrict__ cnt, int N) {
    __shared__ float ls[NGRAPH];
    __shared__ int lc[NGRAPH];
    int tid = threadIdx.x;
    if (tid < NGRAPH) { ls[tid] = 0.f; lc[tid] = 0; }
    __syncthreads();
    int n = blockIdx.x * blockDim.x + tid;
    if (n < N) {
        float a = 0.f;
        int e = rp[n], e1 = rp[n + 1];
        for (; e + 3 < e1; e += 4) {
            int s0 = csr[e], s1 = csr[e + 1], s2 = csr[e + 2], s3 = csr[e + 3];
            a += s[s0] + s[s1] + s[s2] + s[s3];
        }
        for (; e < e1; e++) a += s[csr[e]];
        int g = batch[n];
        atomicAdd(&ls[g], a + t[n]);
        atomicAdd(&lc[g], 1);
    }
    __syncthreads();
    if (tid < NGRAPH && lc[tid] > 0) {
        atomicAdd(&gsum[tid], ls[tid]);
        atomicAdd(&cnt[tid], lc[tid]);
    }
}

__global__ void final_kernel(const float* __restrict__ gsum, const int* __restrict__ cnt,
                             const float* __restrict__ cbuf, const float* __restrict__ head_b,
                             float* __restrict__ out) {
    int g = threadIdx.x;
    if (g < NGRAPH) {
        float c = (float)(cnt[g] > 0 ? cnt[g] : 1);
        out[g] = gsum[g] / c + cbuf[0] + head_b[0];
    }
}

// ---------------- launch ----------------

extern "C" void kernel_launch(void* const* d_in, const int* in_sizes, int n_in,
                              void* d_out, int out_size, void* d_ws, size_t ws_size,
                              hipStream_t stream) {
    const float* x       = (const float*)d_in[0];
    const int*   edge    = (const int*)d_in[1];
    const int*   batch   = (const int*)d_in[2];
    const float* w1_rel  = (const float*)d_in[3];
    const float* w1_root = (const float*)d_in[4];
    const float* b1      = (const float*)d_in[5];
    const float* w2_rel  = (const float*)d_in[6];
    const float* w2_root = (const float*)d_in[7];
    const float* b2      = (const float*)d_in[8];
    const float* w3_rel  = (const float*)d_in[9];
    const float* w3_root = (const float*)d_in[10];
    const float* b3      = (const float*)d_in[11];
    const float* w4_rel  = (const float*)d_in[12];
    const float* w4_root = (const float*)d_in[13];
    const float* b4      = (const float*)d_in[14];
    const float* head_w  = (const float*)d_in[15];
    const float* head_b  = (const float*)d_in[16];
    float* out = (float*)d_out;

    const int N = NNODES, E = NEDGES;
    const int* esrc = edge;
    const int* edst = edge + E;

    char* ws = (char*)d_ws;
    size_t off = 0;
    auto alloc = [&](size_t bytes) -> char* {
        char* p = ws + off;
        off = (off + bytes + 255) & ~(size_t)255;
        return p;
    };
    // zeroed region first (single memset): gsum, cnt, sbuf, tbuf, gcount, done
    float* gsum   = (float*)alloc(NGRAPH * 4);
    int*   cnt    = (int*)alloc(NGRAPH * 4);
    float* sbuf   = (float*)alloc((size_t)N * 4);
    float* tbuf   = (float*)alloc((size_t)N * 4);
    int*   gcount = (int*)alloc(NBUK * 4);
    int*   done   = (int*)alloc(4);
    size_t zero_bytes = off;
    int*   bsum  = (int*)alloc(NBUK * 4);
    int*   roff  = (int*)alloc(NBUK * 4);
    int*   rp    = (int*)alloc((size_t)(N + 1) * 4);
    int*   csr   = (int*)alloc((size_t)E * 4);
    unsigned long long* pedge = (unsigned long long*)alloc((size_t)E * 8);
    unsigned short* xbf    = (unsigned short*)alloc((size_t)N * 128 * 2);
    unsigned short* z1     = (unsigned short*)alloc((size_t)N * 128 * 2);  // [x@w1_rel | x@w1_root]
    unsigned short* combo2 = (unsigned short*)alloc((size_t)N * 128 * 2);  // [agg2 | h1]
    unsigned short* combo3 = (unsigned short*)alloc((size_t)N * 256 * 2);  // [agg3 | h2]
    unsigned short* pL1    = (unsigned short*)alloc(4 * 8 * 512 * 2);      // also DMA overrun slack
    unsigned short* pL2    = (unsigned short*)alloc(4 * 8 * 512 * 2);
    unsigned short* pL3    = (unsigned short*)alloc(6 * 16 * 512 * 2);
    float* wr    = (float*)alloc(192 * 4);
    float* wt    = (float*)alloc(192 * 4);
    float* cbuf  = (float*)alloc(4);
    (void)ws_size;

    hipMemsetAsync(gsum, 0, zero_bytes, stream);

    const int TB = 256;

    // CSR build + prep: histprep (parallel fusion) -> partition -> build
    histprep_kernel<<<NBUK + PREP_NB, 256, 0, stream>>>(
        edst, gcount, bsum, roff, done, x, xbf,
        w1_rel, w1_root, w2_rel, w2_root, w3_rel, w3_root,
        pL1, pL2, pL3, w4_rel, w4_root, b4, head_w, wr, wt, cbuf);
    partition_kernel<<<NBUK, 256, 0, stream>>>(esrc, edst, roff, pedge);
    build_kernel<<<NBUK, 256, 0, stream>>>(pedge, bsum, rp, csr);

    // L1: z1 = xbf @ [w1_rel | w1_root]     (K=128, dout=128, LDS 64KB)
    gemm_v5<8, 4, 1, 0, 8><<<RCHUNK * 8, 256, 0, stream>>>(
        xbf, pL1, nullptr, z1, 128, 0, 0, N, nullptr, nullptr, nullptr, nullptr);
    // h1 = relu( nbrsum(z1[:,:64]) + z1[:,64:] + b1 ) -> combo2[:,64:]
    agg_kernel_v4<8, 2><<<(N * 16 + TB - 1) / TB, TB, 0, stream>>>(z1, 128, rp, csr,
                                                                   z1 + 64, 128, b1, 1, combo2 + 64, 128, N);
    // agg2 = nbrsum(h1) -> combo2[:,:64]
    agg_kernel_v4<8, 2><<<(N * 16 + TB - 1) / TB, TB, 0, stream>>>(combo2 + 64, 128, rp, csr,
                                                                   nullptr, 0, nullptr, 0, combo2, 128, N);
    // L2: h2 = relu(combo2 @ [w2_rel; w2_root] + b2) -> combo3[:,128:]
    gemm_v5<8, 4, 1, 0, 8><<<RCHUNK * 8, 256, 0, stream>>>(
        combo2, pL2, b2, combo3, 256, 128, 1, N, nullptr, nullptr, nullptr, nullptr);
    // agg3 = nbrsum(h2) -> combo3[:,:128]
    agg_kernel_v4<16, 2><<<(N * 32 + TB - 1) / TB, TB, 0, stream>>>(combo3 + 128, 256, rp, csr,
                                                                    nullptr, 0, nullptr, 0, combo3, 256, N);
    // L3 + fused L4 projection (K=256, col-halved, A chunked 16KB, LDS 64KB)
    gemm_v5<16, 3, 2, 1, 4><<<RCHUNK * 8 * 2, 256, 0, stream>>>(
        combo3, pL3, b3, nullptr, 0, 0, 0, N, wr, wt, sbuf, tbuf);

    // pool + head
    aggpool_kernel<<<(N + TB - 1) / TB, TB, 0, stream>>>(sbuf, tbuf, rp, csr, batch, gsum, cnt, N);
    final_kernel<<<1, 64, 0, stream>>>(gsum, cnt, cbuf, head_b, out);
}

// Round 16
// 242.719 us; speedup vs baseline: 3.0177x; 3.0177x over previous
//
#include <hip/hip_runtime.h>

// GraphConv GNN forward, MI355X — Round 16.
// R15 post-mortem: __threadfence() per block = per-XCD L2 writeback on gfx950;
// 6827 of them serialized the chip (555us, VALU 0.2%). GLOBAL LESSON: device-
// scope fences flush L2 on multi-XCD CDNA — at most one, never per-block.
// (Also retro-explains R10's aggpool regression.)
// R16 = R14 verbatim (251.9us, measured twice) + ONE fence-free delta:
// hist+prep merged by parallel block ranges (no cross-block comm, no fence):
// blocks 0..255 -> histogram rows into bcnt (R14 layout); blocks 256+ -> prep.

#define NNODES 50000
#define NEDGES 800000
#define NGRAPH 64
#define NBUK 256                          // dst buckets
#define BSZ 196                           // nodes per bucket (196*256 >= 50000)
#define EPB (NEDGES / NBUK)               // 3125 edges per partition block
#define CVT_NB (NNODES * 128 / 4 / 256)   // 6250
#define PACK_NB (160 * 512 / 256)         // 320
#define PREP_NB (CVT_NB + PACK_NB + 1)    // 6571
#define RGRID ((NNODES + 127) / 128)      // 391 row blocks
#define RCHUNK ((RGRID + 7) / 8)          // 49 chunks of 8 row blocks

typedef __attribute__((ext_vector_type(8))) __bf16 bf16x8;
typedef __attribute__((ext_vector_type(16))) float f32x16;

__device__ __forceinline__ unsigned short f2bf(float f) {
    unsigned u = __float_as_uint(f);
    u += 0x7fff + ((u >> 16) & 1);   // RNE
    return (unsigned short)(u >> 16);
}
__device__ __forceinline__ float bf2f(unsigned b) {
    return __uint_as_float(b << 16);
}

// async 16B global->LDS DMA; LDS dest is wave-uniform base + lane*16 [m104]
__device__ __forceinline__ void dma16(const void* g, void* l) {
    __builtin_amdgcn_global_load_lds(
        (const __attribute__((address_space(1))) void*)g,
        (__attribute__((address_space(3))) void*)l, 16, 0, 0);
}

// ---------------- prep body (cvt / weight pack / head fold) ------------------

__device__ __forceinline__ void pack32(const float* __restrict__ W, unsigned short* __restrict__ dst,
                                       int KS_tot, int ks0, int dcols, int ct0,
                                       int tl, int ksl, int lane, int j) {
    int k = ksl * 16 + ((lane >> 5) << 3) + j;
    int col = tl * 32 + (lane & 31);
    dst[(((size_t)(ct0 + tl) * KS_tot + (ks0 + ksl)) * 64 + lane) * 8 + j] = f2bf(W[k * dcols + col]);
}

__device__ void prep_body(int b, int tid,
                          const float* x, unsigned short* xbf,
                          const float* w1_rel, const float* w1_root,
                          const float* w2_rel, const float* w2_root,
                          const float* w3_rel, const float* w3_root,
                          unsigned short* pL1, unsigned short* pL2, unsigned short* pL3,
                          const float* w4_rel, const float* w4_root,
                          const float* b4, const float* head_w,
                          float* wr, float* wt, float* cbuf) {
    if (b < CVT_NB) {                       // fp32 -> bf16 of x
        int i = b * 256 + tid;
        float4 v = ((const float4*)x)[i];
        unsigned lo = (unsigned)f2bf(v.x) | ((unsigned)f2bf(v.y) << 16);
        unsigned hi = (unsigned)f2bf(v.z) | ((unsigned)f2bf(v.w) << 16);
        ((uint2*)xbf)[i] = make_uint2(lo, hi);
    } else if (b < CVT_NB + PACK_NB) {      // weight packing (32x32x16 B-frag order)
        int idx = (b - CVT_NB) * 256 + tid;
        int g = idx >> 9;
        int t = idx & 511;
        int lane = (t >> 3) & 63, j = t & 7;
        if (g < 16)       { int gl = g;       pack32(w1_rel,  pL1, 8,  0, 64,  0, gl / 8, gl % 8, lane, j); }
        else if (g < 32)  { int gl = g - 16;  pack32(w1_root, pL1, 8,  0, 64,  2, gl / 8, gl % 8, lane, j); }
        else if (g < 48)  { int gl = g - 32;  pack32(w2_rel,  pL2, 8,  0, 128, 0, gl / 4, gl % 4, lane, j); }
        else if (g < 64)  { int gl = g - 48;  pack32(w2_root, pL2, 8,  4, 128, 0, gl / 4, gl % 4, lane, j); }
        else if (g < 112) { int gl = g - 64;  pack32(w3_rel,  pL3, 16, 0, 192, 0, gl / 8, gl % 8, lane, j); }
        else              { int gl = g - 112; pack32(w3_root, pL3, 16, 8, 192, 0, gl / 8, gl % 8, lane, j); }
    } else {                                // head folding
        if (tid < 192) {
            float ar = 0.f, at = 0.f;
            for (int j = 0; j < 64; j++) {
                float hw = head_w[j];
                ar = fmaf(w4_rel[tid * 64 + j], hw, ar);
                at = fmaf(w4_root[tid * 64 + j], hw, at);
            }
            wr[tid] = ar;
            wt[tid] = at;
        } else if (tid == 192) {
            float c = 0.f;
            for (int j = 0; j < 64; j++) c = fmaf(b4[j], head_w[j], c);
            cbuf[0] = c;
        }
    }
}

// ---------------- fused hist + prep: disjoint block ranges, no fences --------

__global__ void __launch_bounds__(256) histprep_kernel(
    const int* __restrict__ edst, int* __restrict__ bcnt,
    const float* __restrict__ x, unsigned short* __restrict__ xbf,
    const float* __restrict__ w1_rel, const float* __restrict__ w1_root,
    const float* __restrict__ w2_rel, const float* __restrict__ w2_root,
    const float* __restrict__ w3_rel, const float* __restrict__ w3_root,
    unsigned short* __restrict__ pL1, unsigned short* __restrict__ pL2,
    unsigned short* __restrict__ pL3,
    const float* __restrict__ w4_rel, const float* __restrict__ w4_root,
    const float* __restrict__ b4, const float* __restrict__ head_w,
    float* __restrict__ wr, float* __restrict__ wt, float* __restrict__ cbuf)
{
    int tid = threadIdx.x, b = blockIdx.x;
    if (b < NBUK) {                          // histogram of edge chunk b (R14 hist)
        __shared__ int h[NBUK];
        h[tid] = 0;
        __syncthreads();
        int end = (b + 1) * EPB;
        for (int i = b * EPB + tid; i < end; i += 256)
            atomicAdd(&h[edst[i] / BSZ], 1);
        __syncthreads();
        bcnt[tid * NBUK + b] = h[tid];
    } else {                                 // prep work, concurrent
        prep_body(b - NBUK, tid, x, xbf, w1_rel, w1_root, w2_rel, w2_root,
                  w3_rel, w3_root, pL1, pL2, pL3, w4_rel, w4_root, b4, head_w,
                  wr, wt, cbuf);
    }
}

// ---------------- scans + partition + build (R14, unchanged) -----------------

__global__ void scan1_kernel(int* __restrict__ a, int* __restrict__ bsum, int n) {
    __shared__ int buf[256];
    int tid = threadIdx.x;
    int i = blockIdx.x * 256 + tid;
    int v = (i < n) ? a[i] : 0;
    buf[tid] = v;
    __syncthreads();
    #pragma unroll
    for (int off = 1; off < 256; off <<= 1) {
        int t = (tid >= off) ? buf[tid - off] : 0;
        __syncthreads();
        buf[tid] += t;
        __syncthreads();
    }
    if (i < n) a[i] = buf[tid] - v;            // local exclusive (in-place)
    if (tid == 255) bsum[blockIdx.x] = buf[255];
}

__global__ void scan2_kernel(int* __restrict__ bsum, int nb) {
    __shared__ int buf[256];
    int tid = threadIdx.x;
    int v = (tid < nb) ? bsum[tid] : 0;
    buf[tid] = v;
    __syncthreads();
    #pragma unroll
    for (int off = 1; off < 256; off <<= 1) {
        int t = (tid >= off) ? buf[tid - off] : 0;
        __syncthreads();
        buf[tid] += t;
        __syncthreads();
    }
    if (tid < nb) bsum[tid] = buf[tid] - v;    // exclusive row offsets
}

__global__ void partition_kernel(const int* __restrict__ src, const int* __restrict__ dst,
                                 const int* __restrict__ cnt, const int* __restrict__ bsum,
                                 unsigned long long* __restrict__ pedge) {
    __shared__ int lbase[NBUK];
    int tid = threadIdx.x, k = blockIdx.x;
    lbase[tid] = cnt[tid * NBUK + k] + bsum[tid];
    __syncthreads();
    int end = (k + 1) * EPB;
    for (int i = k * EPB + tid; i < end; i += 256) {
        int s = src[i], d = dst[i];
        int pos = atomicAdd(&lbase[d / BSZ], 1);
        pedge[pos] = (unsigned long long)(unsigned)s | ((unsigned long long)(unsigned)d << 32);
    }
}

__global__ void build_kernel(const unsigned long long* __restrict__ pedge,
                             const int* __restrict__ bsum,
                             int* __restrict__ rp, int* __restrict__ csr) {
    __shared__ int sdeg[256], sc[256], sbase[256], sfill[256];
    int tid = threadIdx.x, b = blockIdx.x;
    int node0 = b * BSZ;
    int ncnt = NNODES - node0;
    if (ncnt > BSZ) ncnt = BSZ;
    if (ncnt < 0) ncnt = 0;
    int seg0 = bsum[b];
    int seg1 = (b + 1 < NBUK) ? bsum[b + 1] : NEDGES;
    sdeg[tid] = 0;
    sfill[tid] = 0;
    __syncthreads();
    for (int i = seg0 + tid; i < seg1; i += 256)
        atomicAdd(&sdeg[(int)(pedge[i] >> 32) - node0], 1);
    __syncthreads();
    sc[tid] = sdeg[tid];
    __syncthreads();
    #pragma unroll
    for (int off = 1; off < 256; off <<= 1) {
        int t = (tid >= off) ? sc[tid - off] : 0;
        __syncthreads();
        sc[tid] += t;
        __syncthreads();
    }
    sbase[tid] = sc[tid] - sdeg[tid];          // exclusive within bucket
    if (tid < ncnt) rp[node0 + tid] = seg0 + sbase[tid];
    if (b == NBUK - 1 && tid == 0) rp[NNODES] = NEDGES;
    __syncthreads();
    for (int i = seg0 + tid; i < seg1; i += 256) {
        unsigned long long p = pedge[i];
        int d = (int)(p >> 32) - node0;
        int pos = atomicAdd(&sfill[d], 1);
        csr[seg0 + sbase[d] + pos] = (int)(p & 0xffffffffu);
    }
}

// ---------------- MFMA GEMM v5: LDS-resident via async DMA (R12, unchanged) --

template<int KS, int NT, int NHALF, int ST, int KCH>
__global__ __launch_bounds__(256) void gemm_v5(
    const unsigned short* __restrict__ A, const unsigned short* __restrict__ Wall,
    const float* __restrict__ bias, unsigned short* __restrict__ OUT,
    int ldo, int ocol0, int relu, int N,
    const float* __restrict__ wrp, const float* __restrict__ wtp,
    float* __restrict__ sb, float* __restrict__ tb)
{
    const int K = KS * 16;                  // elements (shorts) per row
    const int CPC = KCH * 2;                // 16B chunks per row per A-chunk
    __shared__ __align__(16) unsigned short sB[NT * KS * 512];
    __shared__ __align__(16) unsigned short sA[128 * KCH * 16];

    int i = blockIdx.x;
    int chunk = i / (8 * NHALF);
    int rem = i - chunk * (8 * NHALF);
    int halfsel = rem >> 3;
    int rowb = chunk * 8 + (rem & 7);       // halves of a rowb share blockIdx%8
    int rbase = rowb * 128;
    if (rbase >= N) return;                 // uniform per block

    int tid = threadIdx.x;
    int wave = tid >> 6, lane = tid & 63;
    int l32 = lane & 31, half = lane >> 5;
    const unsigned short* W = Wall + (size_t)halfsel * NT * KS * 512;

    // stage B once (linear)
    #pragma unroll
    for (int j = 0; j < NT * KS * 64 / 256; j++) {
        int p = j * 256 + wave * 64;        // wave-uniform base unit
        dma16(W + ((size_t)p + lane) * 8, sB + (size_t)p * 8);
    }

    f32x16 acc[NT];
    #pragma unroll
    for (int t = 0; t < NT; t++)
        #pragma unroll
        for (int r = 0; r < 16; r++) acc[t][r] = 0.f;

    int lr = wave * 32 + l32;               // local row of this lane's A frags

    for (int kb = 0; kb < KS; kb += KCH) {
        if (kb > 0) __syncthreads();        // protect sA overwrite
        // stage A chunk: 128 rows x KCH ks, XOR-swizzled 16B chunks
        #pragma unroll
        for (int j = 0; j < 128 * CPC / 256; j++) {
            int p = j * 256 + wave * 64 + lane;
            int r = p / CPC;
            int c = p - r * CPC;
            int cg = c ^ (r & (CPC - 1));
            dma16(A + (size_t)(rbase + r) * K + kb * 16 + cg * 8,
                  sA + (size_t)(j * 256 + wave * 64) * 8);
        }
        __syncthreads();                    // drains vmcnt before barrier
        #pragma unroll
        for (int l = 0; l < KCH; l++) {
            int cs = (l * 2 + half) ^ (lr & (CPC - 1));
            bf16x8 a = *(const bf16x8*)(sA + (size_t)lr * (KCH * 16) + cs * 8);
            int ks = kb + l;
            #pragma unroll
            for (int t = 0; t < NT; t++) {
                bf16x8 b = *(const bf16x8*)(sB + ((size_t)(t * KS + ks) * 64 + lane) * 8);
                acc[t] = __builtin_amdgcn_mfma_f32_32x32x16_bf16(a, b, acc[t], 0, 0, 0);
            }
        }
    }

    int wrbase = rbase + wave * 32;
    if constexpr (ST) {
        // fused L4 projection: partial s/t per row via shfl reduce + atomicAdd
        #pragma unroll
        for (int reg = 0; reg < 16; reg++) {
            int row = wrbase + (reg & 3) + 8 * (reg >> 2) + 4 * half;
            float sv = 0.f, tv = 0.f;
            #pragma unroll
            for (int t = 0; t < NT; t++) {
                int col = halfsel * NT * 32 + t * 32 + l32;
                float v = fmaxf(acc[t][reg] + bias[col], 0.f);
                sv = fmaf(v, wrp[col], sv);
                tv = fmaf(v, wtp[col], tv);
            }
            #pragma unroll
            for (int m = 1; m < 32; m <<= 1) {
                sv += __shfl_xor(sv, m, 64);
                tv += __shfl_xor(tv, m, 64);
            }
            if (l32 == 0 && row < N) {
                atomicAdd(&sb[row], sv);
                atomicAdd(&tb[row], tv);
            }
        }
    } else {
        #pragma unroll
        for (int t = 0; t < NT; t++) {
            int col = t * 32 + l32;
            float bi = bias ? bias[col] : 0.f;
            #pragma unroll
            for (int reg = 0; reg < 16; reg++) {
                int row = wrbase + (reg & 3) + 8 * (reg >> 2) + 4 * half;
                if (row < N) {
                    float v = acc[t][reg] + bi;
                    if (relu) v = fmaxf(v, 0.f);
                    OUT[(size_t)row * ldo + ocol0 + col] = f2bf(v);
                }
            }
        }
    }
}

// ---------------- bf16 neighbor-sum via CSR gather (R14, unchanged) ----------

__device__ __forceinline__ void acc8(float* a, uint4 u) {
    a[0] += bf2f(u.x & 0xffffu); a[1] += bf2f(u.x >> 16);
    a[2] += bf2f(u.y & 0xffffu); a[3] += bf2f(u.y >> 16);
    a[4] += bf2f(u.z & 0xffffu); a[5] += bf2f(u.z >> 16);
    a[6] += bf2f(u.w & 0xffffu); a[7] += bf2f(u.w >> 16);
}

template<int LPF, int SUBS>
__global__ void agg_kernel_v4(const unsigned short* __restrict__ X, int ldx,
                              const int* __restrict__ rp, const int* __restrict__ csr,
                              const unsigned short* __restrict__ root, int ldr,
                              const float* __restrict__ bias, int relu,
                              unsigned short* __restrict__ OUT, int ldo, int N) {
    int t = blockIdx.x * blockDim.x + threadIdx.x;
    int node = t / (SUBS * LPF);
    int r = t % (SUBS * LPF);
    int sub = r / LPF;
    int sl = r % LPF;
    if (node >= N) return;
    float a[8] = {0.f, 0.f, 0.f, 0.f, 0.f, 0.f, 0.f, 0.f};
    int e0 = rp[node], e1 = rp[node + 1];
    const unsigned short* xb = X + 8 * sl;
    int e = e0 + sub;
    for (; e + 3 * SUBS < e1; e += 4 * SUBS) {    // 4 independent gathers in flight
        int s0 = csr[e], s1 = csr[e + SUBS], s2 = csr[e + 2 * SUBS], s3 = csr[e + 3 * SUBS];
        uint4 u0 = *(const uint4*)(xb + (size_t)s0 * ldx);
        uint4 u1 = *(const uint4*)(xb + (size_t)s1 * ldx);
        uint4 u2 = *(const uint4*)(xb + (size_t)s2 * ldx);
        uint4 u3 = *(const uint4*)(xb + (size_t)s3 * ldx);
        acc8(a, u0); acc8(a, u1); acc8(a, u2); acc8(a, u3);
    }
    for (; e < e1; e += SUBS) {
        uint4 u = *(const uint4*)(xb + (size_t)csr[e] * ldx);
        acc8(a, u);
    }
    #pragma unroll
    for (int m = LPF; m < SUBS * LPF; m <<= 1)
        #pragma unroll
        for (int i = 0; i < 8; i++) a[i] += __shfl_xor(a[i], m, 64);
    if (sub == 0) {
        if (root) {
            uint4 u = *(const uint4*)(root + (size_t)node * ldr + 8 * sl);
            acc8(a, u);
        }
        if (bias) {
            float4 b0 = *(const float4*)(bias + 8 * sl);
            float4 b1 = *(const float4*)(bias + 8 * sl + 4);
            a[0] += b0.x; a[1] += b0.y; a[2] += b0.z; a[3] += b0.w;
            a[4] += b1.x; a[5] += b1.y; a[6] += b1.z; a[7] += b1.w;
        }
        if (relu) {
            #pragma unroll
            for (int i = 0; i < 8; i++) a[i] = fmaxf(a[i], 0.f);
        }
        uint4 o;
        o.x = (unsigned)f2bf(a[0]) | ((unsigned)f2bf(a[1]) << 16);
        o.y = (unsigned)f2bf(a[2]) | ((unsigned)f2bf(a[3]) << 16);
        o.z = (unsigned)f2bf(a[4]) | ((unsigned)f2bf(a[5]) << 16);
        o.w = (unsigned)f2bf(a[6]) | ((unsigned)f2bf(a[7]) << 16);
        *(uint4*)(OUT + (size_t)node * ldo + 8 * sl) = o;
    }
}

// ---------------- pool + head (R14 shape, unchanged) -------------------------

__global__ void aggpool_kernel(const float* __restrict__ s, const float* __restrict__ t,
                               const int* __restrict__ rp, const int* __restrict__ csr,
                               const int* __restrict__ batch, float* __restrict__ gsum,
                               int* __restrict__ cnt, int N) {
    __shared__ float ls[NGRAPH];
    __shared__ int lc[NGRAPH];
    int tid = threadIdx.x;
    if (tid < NGRAPH) { ls[tid] = 0.f; lc[tid] = 0; }
    __syncthreads();
    int n = blockIdx.x * blockDim.x + tid;
    if (n < N) {
        float a = 0.f;
        int e = rp[n], e1 = rp[n + 1];
        for (; e + 3 < e1; e += 4) {
            int s0 = csr[e], s1 = csr[e + 1], s2 = csr[e + 2], s3 = csr[e + 3];
            a += s[s0] + s[s1] + s[s2] + s[s3];
        }
        for (; e < e1; e++) a += s[csr[e]];
        int g = batch[n];
        atomicAdd(&ls[g], a + t[n]);
        atomicAdd(&lc[g], 1);
    }
    __syncthreads();
    if (tid < NGRAPH && lc[tid] > 0) {
        atomicAdd(&gsum[tid], ls[tid]);
        atomicAdd(&cnt[tid], lc[tid]);
    }
}

__global__ void final_kernel(const float* __restrict__ gsum, const int* __restrict__ cnt,
                             const float* __restrict__ cbuf, const float* __restrict__ head_b,
                             float* __restrict__ out) {
    int g = threadIdx.x;
    if (g < NGRAPH) {
        float c = (float)(cnt[g] > 0 ? cnt[g] : 1);
        out[g] = gsum[g] / c + cbuf[0] + head_b[0];
    }
}

// ---------------- launch ----------------

extern "C" void kernel_launch(void* const* d_in, const int* in_sizes, int n_in,
                              void* d_out, int out_size, void* d_ws, size_t ws_size,
                              hipStream_t stream) {
    const float* x       = (const float*)d_in[0];
    const int*   edge    = (const int*)d_in[1];
    const int*   batch   = (const int*)d_in[2];
    const float* w1_rel  = (const float*)d_in[3];
    const float* w1_root = (const float*)d_in[4];
    const float* b1      = (const float*)d_in[5];
    const float* w2_rel  = (const float*)d_in[6];
    const float* w2_root = (const float*)d_in[7];
    const float* b2      = (const float*)d_in[8];
    const float* w3_rel  = (const float*)d_in[9];
    const float* w3_root = (const float*)d_in[10];
    const float* b3      = (const float*)d_in[11];
    const float* w4_rel  = (const float*)d_in[12];
    const float* w4_root = (const float*)d_in[13];
    const float* b4      = (const float*)d_in[14];
    const float* head_w  = (const float*)d_in[15];
    const float* head_b  = (const float*)d_in[16];
    float* out = (float*)d_out;

    const int N = NNODES, E = NEDGES;
    const int* esrc = edge;
    const int* edst = edge + E;

    char* ws = (char*)d_ws;
    size_t off = 0;
    auto alloc = [&](size_t bytes) -> char* {
        char* p = ws + off;
        off = (off + bytes + 255) & ~(size_t)255;
        return p;
    };
    // zeroed region first (single memset): gsum, cnt, sbuf, tbuf
    float* gsum  = (float*)alloc(NGRAPH * 4);
    int*   cnt   = (int*)alloc(NGRAPH * 4);
    float* sbuf  = (float*)alloc((size_t)N * 4);
    float* tbuf  = (float*)alloc((size_t)N * 4);
    size_t zero_bytes = off;
    int*   bcnt  = (int*)alloc((size_t)NBUK * NBUK * 4);   // bucket x block counts
    int*   bsum  = (int*)alloc(256 * 4);
    int*   rp    = (int*)alloc((size_t)(N + 1) * 4);
    int*   csr   = (int*)alloc((size_t)E * 4);
    unsigned long long* pedge = (unsigned long long*)alloc((size_t)E * 8);
    unsigned short* xbf    = (unsigned short*)alloc((size_t)N * 128 * 2);
    unsigned short* z1     = (unsigned short*)alloc((size_t)N * 128 * 2);  // [x@w1_rel | x@w1_root]
    unsigned short* combo2 = (unsigned short*)alloc((size_t)N * 128 * 2);  // [agg2 | h1]
    unsigned short* combo3 = (unsigned short*)alloc((size_t)N * 256 * 2);  // [agg3 | h2]
    unsigned short* pL1    = (unsigned short*)alloc(4 * 8 * 512 * 2);      // also DMA overrun slack
    unsigned short* pL2    = (unsigned short*)alloc(4 * 8 * 512 * 2);
    unsigned short* pL3    = (unsigned short*)alloc(6 * 16 * 512 * 2);
    float* wr    = (float*)alloc(192 * 4);
    float* wt    = (float*)alloc(192 * 4);
    float* cbuf  = (float*)alloc(4);
    (void)ws_size;

    hipMemsetAsync(gsum, 0, zero_bytes, stream);

    const int TB = 256;

    // CSR build + prep (hist and prep fused by disjoint block ranges)
    histprep_kernel<<<NBUK + PREP_NB, 256, 0, stream>>>(
        edst, bcnt, x, xbf, w1_rel, w1_root, w2_rel, w2_root, w3_rel, w3_root,
        pL1, pL2, pL3, w4_rel, w4_root, b4, head_w, wr, wt, cbuf);
    scan1_kernel<<<NBUK, 256, 0, stream>>>(bcnt, bsum, NBUK * NBUK);
    scan2_kernel<<<1, 256, 0, stream>>>(bsum, NBUK);
    partition_kernel<<<NBUK, 256, 0, stream>>>(esrc, edst, bcnt, bsum, pedge);
    build_kernel<<<NBUK, 256, 0, stream>>>(pedge, bsum, rp, csr);

    // L1: z1 = xbf @ [w1_rel | w1_root]     (K=128, dout=128, LDS 64KB)
    gemm_v5<8, 4, 1, 0, 8><<<RCHUNK * 8, 256, 0, stream>>>(
        xbf, pL1, nullptr, z1, 128, 0, 0, N, nullptr, nullptr, nullptr, nullptr);
    // h1 = relu( nbrsum(z1[:,:64]) + z1[:,64:] + b1 ) -> combo2[:,64:]
    agg_kernel_v4<8, 2><<<(N * 16 + TB - 1) / TB, TB, 0, stream>>>(z1, 128, rp, csr,
                                                                   z1 + 64, 128, b1, 1, combo2 + 64, 128, N);
    // agg2 = nbrsum(h1) -> combo2[:,:64]
    agg_kernel_v4<8, 2><<<(N * 16 + TB - 1) / TB, TB, 0, stream>>>(combo2 + 64, 128, rp, csr,
                                                                   nullptr, 0, nullptr, 0, combo2, 128, N);
    // L2: h2 = relu(combo2 @ [w2_rel; w2_root] + b2) -> combo3[:,128:]
    gemm_v5<8, 4, 1, 0, 8><<<RCHUNK * 8, 256, 0, stream>>>(
        combo2, pL2, b2, combo3, 256, 128, 1, N, nullptr, nullptr, nullptr, nullptr);
    // agg3 = nbrsum(h2) -> combo3[:,:128]
    agg_kernel_v4<16, 2><<<(N * 32 + TB - 1) / TB, TB, 0, stream>>>(combo3 + 128, 256, rp, csr,
                                                                    nullptr, 0, nullptr, 0, combo3, 256, N);
    // L3 + fused L4 projection (K=256, col-halved, A chunked 16KB, LDS 64KB)
    gemm_v5<16, 3, 2, 1, 4><<<RCHUNK * 8 * 2, 256, 0, stream>>>(
        combo3, pL3, b3, nullptr, 0, 0, 0, N, wr, wt, sbuf, tbuf);

    // pool + head
    aggpool_kernel<<<(N + TB - 1) / TB, TB, 0, stream>>>(sbuf, tbuf, rp, csr, batch, gsum, cnt, N);
    final_kernel<<<1, 64, 0, stream>>>(gsum, cnt, cbuf, head_b, out);
}